// Round 1
// baseline (2925.665 us; speedup 1.0000x reference)
//
#include <hip/hip_runtime.h>

#define N_USERS 100000
#define N_ITEMS 100000
#define N_NODES 200000
#define NNZ     3200000
#define EMB     64
#define HOPS    3
#define SLOTS   (HOPS + 1)

// ---------------------------------------------------------------------------
// out[:, 0, :] = concat(user_emb, item_emb)
// ---------------------------------------------------------------------------
__global__ __launch_bounds__(256) void init_ego(
    const float* __restrict__ user_emb,
    const float* __restrict__ item_emb,
    float* __restrict__ out)
{
    int w = (blockIdx.x * blockDim.x + threadIdx.x) >> 6;  // node
    int d = threadIdx.x & 63;
    if (w >= N_NODES) return;
    float v = (w < N_USERS) ? user_emb[(size_t)w * EMB + d]
                            : item_emb[(size_t)(w - N_USERS) * EMB + d];
    out[(size_t)w * SLOTS * EMB + d] = v;
}

// ---------------------------------------------------------------------------
// side[rows[e], :] += vals[e] * ego[cols[e], :]   (ego = out slot k, un-normalized)
// one wave per edge, lane = embedding dim
// ---------------------------------------------------------------------------
__global__ __launch_bounds__(256) void scatter_edges(
    const int* __restrict__ rows,
    const int* __restrict__ cols,
    const float* __restrict__ vals,
    const float* __restrict__ out, int k,
    float* __restrict__ side)
{
    int e = (int)((blockIdx.x * (size_t)blockDim.x + threadIdx.x) >> 6);
    int d = threadIdx.x & 63;
    if (e >= NNZ) return;
    int r = rows[e];
    int c = cols[e];
    float v = vals[e];
    float x = out[(size_t)c * SLOTS * EMB + (size_t)k * EMB + d];
    atomicAdd(&side[(size_t)r * EMB + d], v * x);
}

// ---------------------------------------------------------------------------
// ego_new = leaky_relu(side @ Wg + bg + (ego*side) @ Wb + bb, 0.2)
// written UN-normalized into out slot k+1 (final pass normalizes slots 1..HOPS)
// one wave per node; W matrices staged in LDS (32 KB)
// ---------------------------------------------------------------------------
__global__ __launch_bounds__(256) void transform(
    const float* __restrict__ side,
    const float* __restrict__ Wg, const float* __restrict__ bg,
    const float* __restrict__ Wb, const float* __restrict__ bb,
    float* __restrict__ out, int k)
{
    __shared__ float sWg[EMB * EMB];
    __shared__ float sWb[EMB * EMB];
    __shared__ float sRow[4][EMB];
    __shared__ float esRow[4][EMB];

    int tid = threadIdx.x;
    #pragma unroll
    for (int i = tid; i < EMB * EMB; i += 256) {
        sWg[i] = Wg[i];
        sWb[i] = Wb[i];
    }

    int w = tid >> 6;
    int d = tid & 63;
    int n = blockIdx.x * 4 + w;

    float s = 0.f, es = 0.f;
    if (n < N_NODES) {
        s = side[(size_t)n * EMB + d];
        float e = out[(size_t)n * SLOTS * EMB + (size_t)k * EMB + d];
        es = e * s;
    }
    sRow[w][d] = s;
    esRow[w][d] = es;
    __syncthreads();

    if (n >= N_NODES) return;

    float acc = bg[d] + bb[d];
    #pragma unroll
    for (int j = 0; j < EMB; ++j) {
        acc = fmaf(sRow[w][j], sWg[j * EMB + d], acc);
        acc = fmaf(esRow[w][j], sWb[j * EMB + d], acc);
    }
    float v = (acc > 0.f) ? acc : 0.2f * acc;
    out[(size_t)n * SLOTS * EMB + (size_t)(k + 1) * EMB + d] = v;
}

// ---------------------------------------------------------------------------
// L2-normalize out slots 1..HOPS in place. one wave per (node, slot).
// ---------------------------------------------------------------------------
__global__ __launch_bounds__(256) void normalize_slots(float* __restrict__ out)
{
    int w = (int)((blockIdx.x * (size_t)blockDim.x + threadIdx.x) >> 6);
    int d = threadIdx.x & 63;
    int n = w / HOPS;
    int slot = 1 + (w % HOPS);
    if (n >= N_NODES) return;
    size_t idx = (size_t)n * SLOTS * EMB + (size_t)slot * EMB + d;
    float v = out[idx];
    float ss = v * v;
    #pragma unroll
    for (int off = 32; off > 0; off >>= 1) ss += __shfl_xor(ss, off);
    float nrm = fmaxf(sqrtf(ss), 1e-12f);
    out[idx] = v / nrm;
}

extern "C" void kernel_launch(void* const* d_in, const int* in_sizes, int n_in,
                              void* d_out, int out_size, void* d_ws, size_t ws_size,
                              hipStream_t stream)
{
    const int*   rows     = (const int*)d_in[0];
    const int*   cols     = (const int*)d_in[1];
    const float* vals     = (const float*)d_in[2];
    const float* user_emb = (const float*)d_in[3];
    const float* item_emb = (const float*)d_in[4];
    const float* W_gc     = (const float*)d_in[5];
    const float* b_gc     = (const float*)d_in[6];
    const float* W_bi     = (const float*)d_in[7];
    const float* b_bi     = (const float*)d_in[8];
    float* out  = (float*)d_out;
    float* side = (float*)d_ws;   // N_NODES * EMB floats = 51.2 MB

    // slot 0 = initial ego (not normalized in reference)
    init_ego<<<(N_NODES * 64 + 255) / 256, 256, 0, stream>>>(user_emb, item_emb, out);

    for (int k = 0; k < HOPS; ++k) {
        hipMemsetAsync(side, 0, (size_t)N_NODES * EMB * sizeof(float), stream);
        scatter_edges<<<((size_t)NNZ * 64 + 255) / 256, 256, 0, stream>>>(
            rows, cols, vals, out, k, side);
        transform<<<(N_NODES + 3) / 4, 256, 0, stream>>>(
            side, W_gc + (size_t)k * EMB * EMB, b_gc + (size_t)k * EMB,
            W_bi + (size_t)k * EMB * EMB, b_bi + (size_t)k * EMB, out, k);
    }

    normalize_slots<<<(N_NODES * HOPS * 64 + 255) / 256, 256, 0, stream>>>(out);
}

// Round 2
// 1707.172 us; speedup vs baseline: 1.7137x; 1.7137x over previous
//
#include <hip/hip_runtime.h>

#define N_USERS 100000
#define N_ITEMS 100000
#define N_NODES 200000
#define NNZ     3200000
#define EMB     64
#define HOPS    3
#define SLOTS   (HOPS + 1)

#define SCAN_CHUNK 1024
#define N_CHUNKS   ((N_NODES + SCAN_CHUNK - 1) / SCAN_CHUNK)   // 196

// ---------------------------------------------------------------------------
// out[:, 0, :] = concat(user_emb, item_emb)   (float4 copy)
// ---------------------------------------------------------------------------
__global__ __launch_bounds__(256) void init_ego(
    const float4* __restrict__ user_emb,
    const float4* __restrict__ item_emb,
    float4* __restrict__ out)
{
    int idx = blockIdx.x * blockDim.x + threadIdx.x;   // over N_NODES*16 float4s
    if (idx >= N_NODES * 16) return;
    int n = idx >> 4;
    int q = idx & 15;
    float4 v = (n < N_USERS) ? user_emb[(size_t)n * 16 + q]
                             : item_emb[(size_t)(n - N_USERS) * 16 + q];
    out[(size_t)n * (SLOTS * 16) + q] = v;
}

// ---------------------------------------------------------------------------
// CSR build: histogram of rows
// ---------------------------------------------------------------------------
__global__ __launch_bounds__(256) void hist_rows(
    const int* __restrict__ rows, int* __restrict__ cnt)
{
    int e = blockIdx.x * blockDim.x + threadIdx.x;
    if (e < NNZ) atomicAdd(&cnt[rows[e]], 1);
}

// ---------------------------------------------------------------------------
// scan phase A: per-chunk (1024 elems) partial sums
// ---------------------------------------------------------------------------
__global__ __launch_bounds__(256) void scan_partial(
    const int* __restrict__ cnt, int* __restrict__ partial)
{
    __shared__ int sdata[256];
    int t = threadIdx.x;
    int base = blockIdx.x * SCAN_CHUNK + t * 4;
    int s = 0;
    #pragma unroll
    for (int i = 0; i < 4; ++i) {
        int idx = base + i;
        if (idx < N_NODES) s += cnt[idx];
    }
    sdata[t] = s;
    __syncthreads();
    #pragma unroll
    for (int ofs = 128; ofs > 0; ofs >>= 1) {
        if (t < ofs) sdata[t] += sdata[t + ofs];
        __syncthreads();
    }
    if (t == 0) partial[blockIdx.x] = sdata[0];
}

// ---------------------------------------------------------------------------
// scan phase B: single block, exclusive scan of N_CHUNKS partials
// also writes off[N_NODES] = total
// ---------------------------------------------------------------------------
__global__ __launch_bounds__(256) void scan_mid(
    const int* __restrict__ partial, int* __restrict__ partialOff,
    int* __restrict__ off)
{
    __shared__ int sdata[256];
    int t = threadIdx.x;
    int v = (t < N_CHUNKS) ? partial[t] : 0;
    sdata[t] = v;
    __syncthreads();
    #pragma unroll
    for (int ofs = 1; ofs < 256; ofs <<= 1) {
        int add = (t >= ofs) ? sdata[t - ofs] : 0;
        __syncthreads();
        sdata[t] += add;
        __syncthreads();
    }
    if (t < N_CHUNKS) partialOff[t] = sdata[t] - v;      // exclusive
    if (t == N_CHUNKS - 1) off[N_NODES] = sdata[t];      // total = NNZ
}

// ---------------------------------------------------------------------------
// scan phase C: per-chunk exclusive scan + chunk base -> off[] and cur[]
// ---------------------------------------------------------------------------
__global__ __launch_bounds__(256) void scan_final(
    const int* __restrict__ cnt, const int* __restrict__ partialOff,
    int* __restrict__ off, int* __restrict__ cur)
{
    __shared__ int sdata[256];
    int t = threadIdx.x;
    int base = blockIdx.x * SCAN_CHUNK + t * 4;
    int v0 = 0, v1 = 0, v2 = 0, v3 = 0;
    if (base + 0 < N_NODES) v0 = cnt[base + 0];
    if (base + 1 < N_NODES) v1 = cnt[base + 1];
    if (base + 2 < N_NODES) v2 = cnt[base + 2];
    if (base + 3 < N_NODES) v3 = cnt[base + 3];
    int ts = v0 + v1 + v2 + v3;
    sdata[t] = ts;
    __syncthreads();
    #pragma unroll
    for (int ofs = 1; ofs < 256; ofs <<= 1) {
        int add = (t >= ofs) ? sdata[t - ofs] : 0;
        __syncthreads();
        sdata[t] += add;
        __syncthreads();
    }
    int excl = sdata[t] - ts + partialOff[blockIdx.x];
    int p0 = excl;
    int p1 = p0 + v0;
    int p2 = p1 + v1;
    int p3 = p2 + v2;
    if (base + 0 < N_NODES) { off[base + 0] = p0; cur[base + 0] = p0; }
    if (base + 1 < N_NODES) { off[base + 1] = p1; cur[base + 1] = p1; }
    if (base + 2 < N_NODES) { off[base + 2] = p2; cur[base + 2] = p2; }
    if (base + 3 < N_NODES) { off[base + 3] = p3; cur[base + 3] = p3; }
}

// ---------------------------------------------------------------------------
// CSR fill: permute (col, val) into row-grouped int2 array
// ---------------------------------------------------------------------------
__global__ __launch_bounds__(256) void fill_csr(
    const int* __restrict__ rows, const int* __restrict__ cols,
    const float* __restrict__ vals,
    int* __restrict__ cur, int2* __restrict__ colval)
{
    int e = blockIdx.x * blockDim.x + threadIdx.x;
    if (e >= NNZ) return;
    int r = rows[e];
    int p = atomicAdd(&cur[r], 1);
    int2 cv;
    cv.x = cols[e];
    cv.y = __float_as_int(vals[e]);
    colval[p] = cv;
}

// ---------------------------------------------------------------------------
// Fused hop: side = A@ego (CSR gather), then
//   out[:,k+1,:] = leaky_relu(side@Wg + bg + (ego*side)@Wb + bb, 0.2)
// one wave per row; lane = dim; W columns held in VGPRs; side broadcast via
// v_readlane (uniform -> SGPR operand in the FMA).
// ---------------------------------------------------------------------------
__global__ __launch_bounds__(256) void hop_fused(
    const int* __restrict__ off, const int2* __restrict__ colval,
    const float* __restrict__ Wg, const float* __restrict__ bg,
    const float* __restrict__ Wb, const float* __restrict__ bb,
    float* __restrict__ out, int k)
{
    int d = threadIdx.x & 63;
    int gwave = (int)((blockIdx.x * (size_t)blockDim.x + threadIdx.x) >> 6);
    int nwaves = (gridDim.x * blockDim.x) >> 6;

    float wg[EMB], wb[EMB];
    #pragma unroll
    for (int j = 0; j < EMB; ++j) {
        wg[j] = Wg[j * EMB + d];
        wb[j] = Wb[j * EMB + d];
    }
    float bias = bg[d] + bb[d];

    const float* egoBase = out + (size_t)k * EMB;        // + n*256 + d
    float* dstBase = out + (size_t)(k + 1) * EMB;

    for (int n = gwave; n < N_NODES; n += nwaves) {
        int beg = off[n];
        int end = off[n + 1];
        float acc0 = 0.f, acc1 = 0.f;
        int e = beg;
        for (; e + 2 <= end; e += 2) {
            int2 cv0 = colval[e];
            int2 cv1 = colval[e + 1];
            float x0 = egoBase[(size_t)cv0.x * (SLOTS * EMB) + d];
            float x1 = egoBase[(size_t)cv1.x * (SLOTS * EMB) + d];
            acc0 = fmaf(__int_as_float(cv0.y), x0, acc0);
            acc1 = fmaf(__int_as_float(cv1.y), x1, acc1);
        }
        if (e < end) {
            int2 cv = colval[e];
            float x = egoBase[(size_t)cv.x * (SLOTS * EMB) + d];
            acc0 = fmaf(__int_as_float(cv.y), x, acc0);
        }
        float s = acc0 + acc1;                               // side[n][d]
        float es = egoBase[(size_t)n * (SLOTS * EMB) + d] * s;

        // o_d = bias + sum_j s_j*Wg[j][d] + es_j*Wb[j][d]
        float o0 = bias, o1 = 0.f, o2 = 0.f, o3 = 0.f;
        #pragma unroll
        for (int j = 0; j < EMB; j += 2) {
            float sj0  = __uint_as_float(__builtin_amdgcn_readlane(__float_as_uint(s),  j));
            float esj0 = __uint_as_float(__builtin_amdgcn_readlane(__float_as_uint(es), j));
            float sj1  = __uint_as_float(__builtin_amdgcn_readlane(__float_as_uint(s),  j + 1));
            float esj1 = __uint_as_float(__builtin_amdgcn_readlane(__float_as_uint(es), j + 1));
            o0 = fmaf(sj0,  wg[j],     o0);
            o1 = fmaf(esj0, wb[j],     o1);
            o2 = fmaf(sj1,  wg[j + 1], o2);
            o3 = fmaf(esj1, wb[j + 1], o3);
        }
        float o = (o0 + o1) + (o2 + o3);
        o = (o > 0.f) ? o : 0.2f * o;
        dstBase[(size_t)n * (SLOTS * EMB) + d] = o;
    }
}

// ---------------------------------------------------------------------------
// L2-normalize out slots 1..HOPS in place. one wave per (node, slot).
// ---------------------------------------------------------------------------
__global__ __launch_bounds__(256) void normalize_slots(float* __restrict__ out)
{
    int w = (int)((blockIdx.x * (size_t)blockDim.x + threadIdx.x) >> 6);
    int d = threadIdx.x & 63;
    int n = w / HOPS;
    int slot = 1 + (w % HOPS);
    if (n >= N_NODES) return;
    size_t idx = (size_t)n * SLOTS * EMB + (size_t)slot * EMB + d;
    float v = out[idx];
    float ss = v * v;
    #pragma unroll
    for (int off = 32; off > 0; off >>= 1) ss += __shfl_xor(ss, off);
    float nrm = fmaxf(sqrtf(ss), 1e-12f);
    out[idx] = v / nrm;
}

extern "C" void kernel_launch(void* const* d_in, const int* in_sizes, int n_in,
                              void* d_out, int out_size, void* d_ws, size_t ws_size,
                              hipStream_t stream)
{
    const int*   rows     = (const int*)d_in[0];
    const int*   cols     = (const int*)d_in[1];
    const float* vals     = (const float*)d_in[2];
    const float* user_emb = (const float*)d_in[3];
    const float* item_emb = (const float*)d_in[4];
    const float* W_gc     = (const float*)d_in[5];
    const float* b_gc     = (const float*)d_in[6];
    const float* W_bi     = (const float*)d_in[7];
    const float* b_bi     = (const float*)d_in[8];
    float* out = (float*)d_out;

    // ws layout (4-byte units)
    int* ws_i = (int*)d_ws;
    int* cnt        = ws_i;                     // N_NODES
    int* off        = cnt + N_NODES;            // N_NODES + 1
    int* cur        = off + N_NODES + 1;        // N_NODES
    int* partial    = cur + N_NODES;            // N_CHUNKS
    int* partialOff = partial + N_CHUNKS;       // N_CHUNKS
    int2* colval    = (int2*)(partialOff + N_CHUNKS + 2);  // NNZ int2 (align 8B)

    // --- CSR build ---
    hipMemsetAsync(cnt, 0, N_NODES * sizeof(int), stream);
    hist_rows<<<(NNZ + 255) / 256, 256, 0, stream>>>(rows, cnt);
    scan_partial<<<N_CHUNKS, 256, 0, stream>>>(cnt, partial);
    scan_mid<<<1, 256, 0, stream>>>(partial, partialOff, off);
    scan_final<<<N_CHUNKS, 256, 0, stream>>>(cnt, partialOff, off, cur);
    fill_csr<<<(NNZ + 255) / 256, 256, 0, stream>>>(rows, cols, vals, cur, colval);

    // --- slot 0 = initial ego ---
    init_ego<<<(N_NODES * 16 + 255) / 256, 256, 0, stream>>>(
        (const float4*)user_emb, (const float4*)item_emb, (float4*)out);

    // --- hops ---
    for (int k = 0; k < HOPS; ++k) {
        hop_fused<<<2048, 256, 0, stream>>>(
            off, colval,
            W_gc + (size_t)k * EMB * EMB, b_gc + (size_t)k * EMB,
            W_bi + (size_t)k * EMB * EMB, b_bi + (size_t)k * EMB,
            out, k);
    }

    normalize_slots<<<(N_NODES * HOPS * 64 + 255) / 256, 256, 0, stream>>>(out);
}

// Round 3
// 1070.361 us; speedup vs baseline: 2.7333x; 1.5949x over previous
//
#include <hip/hip_runtime.h>

#define N_USERS 100000
#define N_ITEMS 100000
#define N_NODES 200000
#define NNZ     3200000
#define EMB     64
#define HOPS    3
#define SLOTS   (HOPS + 1)
#define ROWSTRIDE (SLOTS * EMB)   // 256 floats per node row in out

#define SCAN_CHUNK 1024
#define N_CHUNKS   ((N_NODES + SCAN_CHUNK - 1) / SCAN_CHUNK)   // 196

// ---------------------------------------------------------------------------
// out[:, 0, :] = concat(user_emb, item_emb)   (float4 copy)
// ---------------------------------------------------------------------------
__global__ __launch_bounds__(256) void init_ego(
    const float4* __restrict__ user_emb,
    const float4* __restrict__ item_emb,
    float4* __restrict__ out)
{
    int idx = blockIdx.x * blockDim.x + threadIdx.x;   // over N_NODES*16 float4s
    if (idx >= N_NODES * 16) return;
    int n = idx >> 4;
    int q = idx & 15;
    float4 v = (n < N_USERS) ? user_emb[(size_t)n * 16 + q]
                             : item_emb[(size_t)(n - N_USERS) * 16 + q];
    out[(size_t)n * (SLOTS * 16) + q] = v;
}

// ---------------------------------------------------------------------------
// CSR build: histogram of rows
// ---------------------------------------------------------------------------
__global__ __launch_bounds__(256) void hist_rows(
    const int* __restrict__ rows, int* __restrict__ cnt)
{
    int e = blockIdx.x * blockDim.x + threadIdx.x;
    if (e < NNZ) atomicAdd(&cnt[rows[e]], 1);
}

__global__ __launch_bounds__(256) void scan_partial(
    const int* __restrict__ cnt, int* __restrict__ partial)
{
    __shared__ int sdata[256];
    int t = threadIdx.x;
    int base = blockIdx.x * SCAN_CHUNK + t * 4;
    int s = 0;
    #pragma unroll
    for (int i = 0; i < 4; ++i) {
        int idx = base + i;
        if (idx < N_NODES) s += cnt[idx];
    }
    sdata[t] = s;
    __syncthreads();
    #pragma unroll
    for (int ofs = 128; ofs > 0; ofs >>= 1) {
        if (t < ofs) sdata[t] += sdata[t + ofs];
        __syncthreads();
    }
    if (t == 0) partial[blockIdx.x] = sdata[0];
}

__global__ __launch_bounds__(256) void scan_mid(
    const int* __restrict__ partial, int* __restrict__ partialOff,
    int* __restrict__ off)
{
    __shared__ int sdata[256];
    int t = threadIdx.x;
    int v = (t < N_CHUNKS) ? partial[t] : 0;
    sdata[t] = v;
    __syncthreads();
    #pragma unroll
    for (int ofs = 1; ofs < 256; ofs <<= 1) {
        int add = (t >= ofs) ? sdata[t - ofs] : 0;
        __syncthreads();
        sdata[t] += add;
        __syncthreads();
    }
    if (t < N_CHUNKS) partialOff[t] = sdata[t] - v;      // exclusive
    if (t == N_CHUNKS - 1) off[N_NODES] = sdata[t];      // total = NNZ
}

__global__ __launch_bounds__(256) void scan_final(
    const int* __restrict__ cnt, const int* __restrict__ partialOff,
    int* __restrict__ off, int* __restrict__ cur)
{
    __shared__ int sdata[256];
    int t = threadIdx.x;
    int base = blockIdx.x * SCAN_CHUNK + t * 4;
    int v0 = 0, v1 = 0, v2 = 0, v3 = 0;
    if (base + 0 < N_NODES) v0 = cnt[base + 0];
    if (base + 1 < N_NODES) v1 = cnt[base + 1];
    if (base + 2 < N_NODES) v2 = cnt[base + 2];
    if (base + 3 < N_NODES) v3 = cnt[base + 3];
    int ts = v0 + v1 + v2 + v3;
    sdata[t] = ts;
    __syncthreads();
    #pragma unroll
    for (int ofs = 1; ofs < 256; ofs <<= 1) {
        int add = (t >= ofs) ? sdata[t - ofs] : 0;
        __syncthreads();
        sdata[t] += add;
        __syncthreads();
    }
    int excl = sdata[t] - ts + partialOff[blockIdx.x];
    int p0 = excl;
    int p1 = p0 + v0;
    int p2 = p1 + v1;
    int p3 = p2 + v2;
    if (base + 0 < N_NODES) { off[base + 0] = p0; cur[base + 0] = p0; }
    if (base + 1 < N_NODES) { off[base + 1] = p1; cur[base + 1] = p1; }
    if (base + 2 < N_NODES) { off[base + 2] = p2; cur[base + 2] = p2; }
    if (base + 3 < N_NODES) { off[base + 3] = p3; cur[base + 3] = p3; }
}

__global__ __launch_bounds__(256) void fill_csr(
    const int* __restrict__ rows, const int* __restrict__ cols,
    const float* __restrict__ vals,
    int* __restrict__ cur, int2* __restrict__ colval)
{
    int e = blockIdx.x * blockDim.x + threadIdx.x;
    if (e >= NNZ) return;
    int r = rows[e];
    int p = atomicAdd(&cur[r], 1);
    int2 cv;
    cv.x = cols[e];
    cv.y = __float_as_int(vals[e]);
    colval[p] = cv;
}

// ---------------------------------------------------------------------------
// gather: side[n][d] = sum_e vals[e]*ego[cols[e]][d], written to out slot k+1
// (slot k+1 is later overwritten in place by transform_fused).
// one wave per row; 8-deep unrolled gather for MLP; scalar colval loads.
// ---------------------------------------------------------------------------
__global__ __launch_bounds__(256, 4) void gather_side(
    const int* __restrict__ off, const int2* __restrict__ colval,
    float* __restrict__ out, int k)
{
    int d = threadIdx.x & 63;
    int gw = (int)((blockIdx.x * (size_t)blockDim.x + threadIdx.x) >> 6);
    int nw = (gridDim.x * blockDim.x) >> 6;

    const float* egoK = out + (size_t)k * EMB;           // + n*256 + d
    float* dst = out + (size_t)(k + 1) * EMB;

    for (int n = gw; n < N_NODES; n += nw) {
        int beg = __builtin_amdgcn_readfirstlane(off[n]);
        int end = __builtin_amdgcn_readfirstlane(off[n + 1]);
        float a0 = 0.f, a1 = 0.f, a2 = 0.f, a3 = 0.f;
        int e = beg;
        for (; e + 8 <= end; e += 8) {
            int2 cv[8];
            #pragma unroll
            for (int u = 0; u < 8; ++u) cv[u] = colval[e + u];
            float x[8];
            #pragma unroll
            for (int u = 0; u < 8; ++u)
                x[u] = egoK[(unsigned)cv[u].x * (unsigned)ROWSTRIDE + (unsigned)d];
            a0 = fmaf(__int_as_float(cv[0].y), x[0], a0);
            a1 = fmaf(__int_as_float(cv[1].y), x[1], a1);
            a2 = fmaf(__int_as_float(cv[2].y), x[2], a2);
            a3 = fmaf(__int_as_float(cv[3].y), x[3], a3);
            a0 = fmaf(__int_as_float(cv[4].y), x[4], a0);
            a1 = fmaf(__int_as_float(cv[5].y), x[5], a1);
            a2 = fmaf(__int_as_float(cv[6].y), x[6], a2);
            a3 = fmaf(__int_as_float(cv[7].y), x[7], a3);
        }
        for (; e + 2 <= end; e += 2) {
            int2 c0 = colval[e];
            int2 c1 = colval[e + 1];
            float x0 = egoK[(unsigned)c0.x * (unsigned)ROWSTRIDE + (unsigned)d];
            float x1 = egoK[(unsigned)c1.x * (unsigned)ROWSTRIDE + (unsigned)d];
            a0 = fmaf(__int_as_float(c0.y), x0, a0);
            a1 = fmaf(__int_as_float(c1.y), x1, a1);
        }
        if (e < end) {
            int2 c = colval[e];
            a2 = fmaf(__int_as_float(c.y),
                      egoK[(unsigned)c.x * (unsigned)ROWSTRIDE + (unsigned)d], a2);
        }
        dst[(size_t)n * ROWSTRIDE + d] = (a0 + a1) + (a2 + a3);
    }
}

// ---------------------------------------------------------------------------
// transform (+fused normalization):
//   o = leaky_relu(side@Wg + bg + (ego*side)@Wb + bb, 0.2)
//   slot k+1 <- o            (normalized if k is the last hop)
//   slot k   <- ego/||ego||  (for k>=1: slot k fully consumed by now)
// W columns pinned in VGPRs (128 regs) via __launch_bounds__(256,2).
// ---------------------------------------------------------------------------
__global__ __launch_bounds__(256, 2) void transform_fused(
    const float* __restrict__ Wg, const float* __restrict__ bg,
    const float* __restrict__ Wb, const float* __restrict__ bb,
    float* __restrict__ out, int k)
{
    int d = threadIdx.x & 63;
    int gw = (int)((blockIdx.x * (size_t)blockDim.x + threadIdx.x) >> 6);
    int nw = (gridDim.x * blockDim.x) >> 6;

    float wg[EMB], wb[EMB];
    #pragma unroll
    for (int j = 0; j < EMB; ++j) {
        wg[j] = Wg[j * EMB + d];
        wb[j] = Wb[j * EMB + d];
    }
    float bias = bg[d] + bb[d];

    float* slotK  = out + (size_t)k * EMB;
    float* slotK1 = out + (size_t)(k + 1) * EMB;
    const bool lastHop = (k == HOPS - 1);

    for (int n = gw; n < N_NODES; n += nw) {
        size_t base = (size_t)n * ROWSTRIDE;
        float s  = slotK1[base + d];       // side (staged by gather_side)
        float eg = slotK [base + d];       // un-normalized ego
        float es = eg * s;

        float o0 = bias, o1 = 0.f, o2 = 0.f, o3 = 0.f;
        #pragma unroll
        for (int j = 0; j < EMB; j += 2) {
            float sj0 = __uint_as_float(__builtin_amdgcn_readlane(__float_as_uint(s),  j));
            float ej0 = __uint_as_float(__builtin_amdgcn_readlane(__float_as_uint(es), j));
            float sj1 = __uint_as_float(__builtin_amdgcn_readlane(__float_as_uint(s),  j + 1));
            float ej1 = __uint_as_float(__builtin_amdgcn_readlane(__float_as_uint(es), j + 1));
            o0 = fmaf(sj0, wg[j],     o0);
            o1 = fmaf(ej0, wb[j],     o1);
            o2 = fmaf(sj1, wg[j + 1], o2);
            o3 = fmaf(ej1, wb[j + 1], o3);
        }
        float o = (o0 + o1) + (o2 + o3);
        o = (o > 0.f) ? o : 0.2f * o;

        if (lastHop) {
            float ss = o * o;
            #pragma unroll
            for (int m = 32; m > 0; m >>= 1) ss += __shfl_xor(ss, m);
            o = o / fmaxf(sqrtf(ss), 1e-12f);
        }
        slotK1[base + d] = o;

        if (k >= 1) {
            float ss = eg * eg;
            #pragma unroll
            for (int m = 32; m > 0; m >>= 1) ss += __shfl_xor(ss, m);
            slotK[base + d] = eg / fmaxf(sqrtf(ss), 1e-12f);
        }
    }
}

extern "C" void kernel_launch(void* const* d_in, const int* in_sizes, int n_in,
                              void* d_out, int out_size, void* d_ws, size_t ws_size,
                              hipStream_t stream)
{
    const int*   rows     = (const int*)d_in[0];
    const int*   cols     = (const int*)d_in[1];
    const float* vals     = (const float*)d_in[2];
    const float* user_emb = (const float*)d_in[3];
    const float* item_emb = (const float*)d_in[4];
    const float* W_gc     = (const float*)d_in[5];
    const float* b_gc     = (const float*)d_in[6];
    const float* W_bi     = (const float*)d_in[7];
    const float* b_bi     = (const float*)d_in[8];
    float* out = (float*)d_out;

    // ws layout (4-byte units)
    int* ws_i = (int*)d_ws;
    int* cnt        = ws_i;                     // N_NODES
    int* off        = cnt + N_NODES;            // N_NODES + 1
    int* cur        = off + N_NODES + 1;        // N_NODES
    int* partial    = cur + N_NODES;            // N_CHUNKS
    int* partialOff = partial + N_CHUNKS;       // N_CHUNKS
    int2* colval    = (int2*)(partialOff + N_CHUNKS + 2);  // NNZ int2

    // --- CSR build ---
    hipMemsetAsync(cnt, 0, N_NODES * sizeof(int), stream);
    hist_rows<<<(NNZ + 255) / 256, 256, 0, stream>>>(rows, cnt);
    scan_partial<<<N_CHUNKS, 256, 0, stream>>>(cnt, partial);
    scan_mid<<<1, 256, 0, stream>>>(partial, partialOff, off);
    scan_final<<<N_CHUNKS, 256, 0, stream>>>(cnt, partialOff, off, cur);
    fill_csr<<<(NNZ + 255) / 256, 256, 0, stream>>>(rows, cols, vals, cur, colval);

    // --- slot 0 = initial ego ---
    init_ego<<<(N_NODES * 16 + 255) / 256, 256, 0, stream>>>(
        (const float4*)user_emb, (const float4*)item_emb, (float4*)out);

    // --- hops: gather into slot k+1, transform in place (+norm of slot k) ---
    for (int k = 0; k < HOPS; ++k) {
        gather_side<<<2048, 256, 0, stream>>>(off, colval, out, k);
        transform_fused<<<1024, 256, 0, stream>>>(
            W_gc + (size_t)k * EMB * EMB, b_gc + (size_t)k * EMB,
            W_bi + (size_t)k * EMB * EMB, b_bi + (size_t)k * EMB,
            out, k);
    }
}

// Round 4
// 963.109 us; speedup vs baseline: 3.0377x; 1.1114x over previous
//
#include <hip/hip_runtime.h>

#define N_USERS 100000
#define N_ITEMS 100000
#define N_NODES 200000
#define NNZ     3200000
#define EMB     64
#define HOPS    3
#define SLOTS   (HOPS + 1)
#define ROWSTRIDE (SLOTS * EMB)   // 256 floats per node row in out

#define BROWS 1024                               // rows per bucket
#define NBUCK ((N_NODES + BROWS - 1) / BROWS)    // 196
#define CAPA  32                                 // LDS slots per bucket (bucketize)
#define CAPB  20                                 // reg entries per thread (csr_bucket)
                                                 // covers bucket count <= 20480
                                                 // (mean 16384, sigma ~128 -> +32 sigma)

// pack: x = (rlocal<<18) | col   (rlocal<1024 -> 10b, col<200000<2^18 -> 18b)

// ---------------------------------------------------------------------------
// out[:, 0, :] = concat(user_emb, item_emb)   (float4 copy)
// ---------------------------------------------------------------------------
__global__ __launch_bounds__(256) void init_ego(
    const float4* __restrict__ user_emb,
    const float4* __restrict__ item_emb,
    float4* __restrict__ out)
{
    int idx = blockIdx.x * blockDim.x + threadIdx.x;
    if (idx >= N_NODES * 16) return;
    int n = idx >> 4;
    int q = idx & 15;
    float4 v = (n < N_USERS) ? user_emb[(size_t)n * 16 + q]
                             : item_emb[(size_t)(n - N_USERS) * 16 + q];
    out[(size_t)n * (SLOTS * 16) + q] = v;
}

// ---------------------------------------------------------------------------
// bucket histogram: bcnt[b] = #edges with rows[e]>>10 == b  (LDS-staged)
// ---------------------------------------------------------------------------
__global__ __launch_bounds__(256) void hist_buckets(
    const int* __restrict__ rows, int* __restrict__ bcnt)
{
    __shared__ int h[NBUCK];
    int t = threadIdx.x;
    if (t < NBUCK) h[t] = 0;
    __syncthreads();
    for (int e = blockIdx.x * blockDim.x + t; e < NNZ; e += gridDim.x * blockDim.x)
        atomicAdd(&h[rows[e] >> 10], 1);
    __syncthreads();
    if (t < NBUCK && h[t]) atomicAdd(&bcnt[t], h[t]);
}

// ---------------------------------------------------------------------------
// exclusive scan of 196 bucket counts -> boff[0..NBUCK], gcur init, off[N]
// ---------------------------------------------------------------------------
__global__ __launch_bounds__(256) void scan196(
    const int* __restrict__ bcnt, int* __restrict__ boff,
    int* __restrict__ gcur, int* __restrict__ off)
{
    __shared__ int sdata[256];
    int t = threadIdx.x;
    int v = (t < NBUCK) ? bcnt[t] : 0;
    sdata[t] = v;
    __syncthreads();
    #pragma unroll
    for (int ofs = 1; ofs < 256; ofs <<= 1) {
        int add = (t >= ofs) ? sdata[t - ofs] : 0;
        __syncthreads();
        sdata[t] += add;
        __syncthreads();
    }
    if (t < NBUCK) {
        int excl = sdata[t] - v;
        boff[t] = excl;
        gcur[t] = excl;
    }
    if (t == NBUCK - 1) boff[NBUCK] = sdata[t];   // = NNZ
    if (t == 0) off[N_NODES] = NNZ;
}

// ---------------------------------------------------------------------------
// bucketize: scatter packed edges into bucket-grouped tmp[] with LDS staging
// so global writes are 16-entry (128 B) contiguous flushes.
// ---------------------------------------------------------------------------
__global__ __launch_bounds__(256) void bucketize(
    const int* __restrict__ rows, const int* __restrict__ cols,
    const float* __restrict__ vals,
    int* __restrict__ gcur, int2* __restrict__ tmp)
{
    __shared__ int2 buf[NBUCK][CAPA];   // ~50 KB
    __shared__ int lcnt[NBUCK];

    int t = threadIdx.x;
    if (t < NBUCK) lcnt[t] = 0;
    __syncthreads();

    const int chunk = (NNZ + gridDim.x - 1) / gridDim.x;
    int s = blockIdx.x * chunk;
    int e = min(s + chunk, NNZ);

    for (int base = s; base < e; base += 256) {
        int idx = base + t;
        bool pending = false;
        int b = 0;
        int2 pk;
        if (idx < e) {
            int r = rows[idx];
            int c = cols[idx];
            float v = vals[idx];
            b = r >> 10;
            pk.x = ((r & 1023) << 18) | c;
            pk.y = __float_as_int(v);
            int pos = atomicAdd(&lcnt[b], 1);
            if (pos < CAPA) buf[b][pos] = pk;
            else            pending = true;           // rare overflow
        }
        if (pending) {                                // direct (uncoalesced) store
            int p = atomicAdd(&gcur[b], 1);
            tmp[p] = pk;
        }
        __syncthreads();
        if (t < NBUCK) {
            int cnt = lcnt[t]; if (cnt > CAPA) cnt = CAPA;
            int nf = cnt & ~15;
            if (nf > 0) {
                int g = atomicAdd(&gcur[t], nf);
                for (int i = 0; i < nf; ++i) tmp[g + i] = buf[t][i];
                int rem = cnt - nf;
                for (int i = 0; i < rem; ++i) buf[t][i] = buf[t][nf + i];
                lcnt[t] = rem;
            } else {
                lcnt[t] = cnt;
            }
        }
        __syncthreads();
    }
    // final residual flush
    if (t < NBUCK) {
        int cnt = lcnt[t]; if (cnt > CAPA) cnt = CAPA;
        if (cnt > 0) {
            int g = atomicAdd(&gcur[t], cnt);
            for (int i = 0; i < cnt; ++i) tmp[g + i] = buf[t][i];
        }
    }
}

// ---------------------------------------------------------------------------
// csr_bucket: one block per bucket. Loads the bucket's edges into registers
// (in-place safe), builds per-row counts + scan in LDS, writes off[], then
// scatters final CSR (col,val) into the bucket's own range (L2-resident).
// ---------------------------------------------------------------------------
__global__ __launch_bounds__(1024) void csr_bucket(
    const int* __restrict__ boff, int2* __restrict__ colval,
    int* __restrict__ off)
{
    __shared__ int curL[BROWS];
    __shared__ int sWaveSum[16];
    __shared__ int sWaveOff[16];

    int b = blockIdx.x;
    int t = threadIdx.x;
    int s = boff[b];
    int e = boff[b + 1];

    // load my entries (all reads precede all writes -> in-place permutation ok)
    int2 ent[CAPB];
    #pragma unroll
    for (int i = 0; i < CAPB; ++i) {
        int idx = s + i * 1024 + t;
        if (idx < e) ent[i] = colval[idx];
    }

    curL[t] = 0;
    __syncthreads();

    #pragma unroll
    for (int i = 0; i < CAPB; ++i) {
        int idx = s + i * 1024 + t;
        if (idx < e) atomicAdd(&curL[ent[i].x >> 18], 1);
    }
    __syncthreads();

    // exclusive scan of curL[0..1024)
    int lane = t & 63;
    int wid  = t >> 6;
    int v = curL[t];
    int inc = v;
    #pragma unroll
    for (int o = 1; o < 64; o <<= 1) {
        int up = __shfl_up(inc, o);
        if (lane >= o) inc += up;
    }
    if (lane == 63) sWaveSum[wid] = inc;
    __syncthreads();
    if (t < 16) {
        int w = sWaveSum[t];
        int wi = w;
        #pragma unroll
        for (int o = 1; o < 16; o <<= 1) {
            int up = __shfl_up(wi, o);
            if (t >= o) wi += up;
        }
        sWaveOff[t] = wi - w;
    }
    __syncthreads();
    int excl = inc - v + sWaveOff[wid];

    int row = b * BROWS + t;
    if (row < N_NODES) off[row] = s + excl;
    __syncthreads();            // everyone done reading curL counts
    curL[t] = s + excl;
    __syncthreads();

    #pragma unroll
    for (int i = 0; i < CAPB; ++i) {
        int idx = s + i * 1024 + t;
        if (idx < e) {
            int rl = ent[i].x >> 18;
            int p = atomicAdd(&curL[rl], 1);
            int2 cv;
            cv.x = ent[i].x & 0x3FFFF;
            cv.y = ent[i].y;
            colval[p] = cv;
        }
    }
}

// ---------------------------------------------------------------------------
// gather: side[n][d] = sum_e vals[e]*ego[cols[e]][d], written to out slot k+1
// ---------------------------------------------------------------------------
__global__ __launch_bounds__(256, 4) void gather_side(
    const int* __restrict__ off, const int2* __restrict__ colval,
    float* __restrict__ out, int k)
{
    int d = threadIdx.x & 63;
    int gw = (int)((blockIdx.x * (size_t)blockDim.x + threadIdx.x) >> 6);
    int nw = (gridDim.x * blockDim.x) >> 6;

    const float* egoK = out + (size_t)k * EMB;
    float* dst = out + (size_t)(k + 1) * EMB;

    for (int n = gw; n < N_NODES; n += nw) {
        int beg = __builtin_amdgcn_readfirstlane(off[n]);
        int end = __builtin_amdgcn_readfirstlane(off[n + 1]);
        float a0 = 0.f, a1 = 0.f, a2 = 0.f, a3 = 0.f;
        int e = beg;
        for (; e + 8 <= end; e += 8) {
            int2 cv[8];
            #pragma unroll
            for (int u = 0; u < 8; ++u) cv[u] = colval[e + u];
            float x[8];
            #pragma unroll
            for (int u = 0; u < 8; ++u)
                x[u] = egoK[(unsigned)cv[u].x * (unsigned)ROWSTRIDE + (unsigned)d];
            a0 = fmaf(__int_as_float(cv[0].y), x[0], a0);
            a1 = fmaf(__int_as_float(cv[1].y), x[1], a1);
            a2 = fmaf(__int_as_float(cv[2].y), x[2], a2);
            a3 = fmaf(__int_as_float(cv[3].y), x[3], a3);
            a0 = fmaf(__int_as_float(cv[4].y), x[4], a0);
            a1 = fmaf(__int_as_float(cv[5].y), x[5], a1);
            a2 = fmaf(__int_as_float(cv[6].y), x[6], a2);
            a3 = fmaf(__int_as_float(cv[7].y), x[7], a3);
        }
        for (; e + 2 <= end; e += 2) {
            int2 c0 = colval[e];
            int2 c1 = colval[e + 1];
            float x0 = egoK[(unsigned)c0.x * (unsigned)ROWSTRIDE + (unsigned)d];
            float x1 = egoK[(unsigned)c1.x * (unsigned)ROWSTRIDE + (unsigned)d];
            a0 = fmaf(__int_as_float(c0.y), x0, a0);
            a1 = fmaf(__int_as_float(c1.y), x1, a1);
        }
        if (e < end) {
            int2 c = colval[e];
            a2 = fmaf(__int_as_float(c.y),
                      egoK[(unsigned)c.x * (unsigned)ROWSTRIDE + (unsigned)d], a2);
        }
        dst[(size_t)n * ROWSTRIDE + d] = (a0 + a1) + (a2 + a3);
    }
}

// ---------------------------------------------------------------------------
// transform (+fused normalization)
// ---------------------------------------------------------------------------
__global__ __launch_bounds__(256, 2) void transform_fused(
    const float* __restrict__ Wg, const float* __restrict__ bg,
    const float* __restrict__ Wb, const float* __restrict__ bb,
    float* __restrict__ out, int k)
{
    int d = threadIdx.x & 63;
    int gw = (int)((blockIdx.x * (size_t)blockDim.x + threadIdx.x) >> 6);
    int nw = (gridDim.x * blockDim.x) >> 6;

    float wg[EMB], wb[EMB];
    #pragma unroll
    for (int j = 0; j < EMB; ++j) {
        wg[j] = Wg[j * EMB + d];
        wb[j] = Wb[j * EMB + d];
    }
    float bias = bg[d] + bb[d];

    float* slotK  = out + (size_t)k * EMB;
    float* slotK1 = out + (size_t)(k + 1) * EMB;
    const bool lastHop = (k == HOPS - 1);

    for (int n = gw; n < N_NODES; n += nw) {
        size_t base = (size_t)n * ROWSTRIDE;
        float s  = slotK1[base + d];
        float eg = slotK [base + d];
        float es = eg * s;

        float o0 = bias, o1 = 0.f, o2 = 0.f, o3 = 0.f;
        #pragma unroll
        for (int j = 0; j < EMB; j += 2) {
            float sj0 = __uint_as_float(__builtin_amdgcn_readlane(__float_as_uint(s),  j));
            float ej0 = __uint_as_float(__builtin_amdgcn_readlane(__float_as_uint(es), j));
            float sj1 = __uint_as_float(__builtin_amdgcn_readlane(__float_as_uint(s),  j + 1));
            float ej1 = __uint_as_float(__builtin_amdgcn_readlane(__float_as_uint(es), j + 1));
            o0 = fmaf(sj0, wg[j],     o0);
            o1 = fmaf(ej0, wb[j],     o1);
            o2 = fmaf(sj1, wg[j + 1], o2);
            o3 = fmaf(ej1, wb[j + 1], o3);
        }
        float o = (o0 + o1) + (o2 + o3);
        o = (o > 0.f) ? o : 0.2f * o;

        if (lastHop) {
            float ss = o * o;
            #pragma unroll
            for (int m = 32; m > 0; m >>= 1) ss += __shfl_xor(ss, m);
            o = o / fmaxf(sqrtf(ss), 1e-12f);
        }
        slotK1[base + d] = o;

        if (k >= 1) {
            float ss = eg * eg;
            #pragma unroll
            for (int m = 32; m > 0; m >>= 1) ss += __shfl_xor(ss, m);
            slotK[base + d] = eg / fmaxf(sqrtf(ss), 1e-12f);
        }
    }
}

extern "C" void kernel_launch(void* const* d_in, const int* in_sizes, int n_in,
                              void* d_out, int out_size, void* d_ws, size_t ws_size,
                              hipStream_t stream)
{
    const int*   rows     = (const int*)d_in[0];
    const int*   cols     = (const int*)d_in[1];
    const float* vals     = (const float*)d_in[2];
    const float* user_emb = (const float*)d_in[3];
    const float* item_emb = (const float*)d_in[4];
    const float* W_gc     = (const float*)d_in[5];
    const float* b_gc     = (const float*)d_in[6];
    const float* W_bi     = (const float*)d_in[7];
    const float* b_bi     = (const float*)d_in[8];
    float* out = (float*)d_out;

    // ws layout (ints): bcnt[196] | boff[197] | gcur[196] | off[N+1] | colval[NNZ int2]
    int* ws_i = (int*)d_ws;
    int* bcnt = ws_i;                        // NBUCK
    int* boff = bcnt + NBUCK;                // NBUCK + 1
    int* gcur = boff + NBUCK + 1;            // NBUCK
    int* off  = gcur + NBUCK;                // N_NODES + 1
    int2* colval = (int2*)(off + N_NODES + 1);   // NNZ (8B-aligned: 200590 ints before)

    // --- CSR build (two-level, cache-shaped) ---
    hipMemsetAsync(bcnt, 0, NBUCK * sizeof(int), stream);
    hist_buckets<<<1024, 256, 0, stream>>>(rows, bcnt);
    scan196<<<1, 256, 0, stream>>>(bcnt, boff, gcur, off);
    bucketize<<<512, 256, 0, stream>>>(rows, cols, vals, gcur, colval);
    csr_bucket<<<NBUCK, 1024, 0, stream>>>(boff, colval, off);

    // --- slot 0 = initial ego ---
    init_ego<<<(N_NODES * 16 + 255) / 256, 256, 0, stream>>>(
        (const float4*)user_emb, (const float4*)item_emb, (float4*)out);

    // --- hops ---
    for (int k = 0; k < HOPS; ++k) {
        gather_side<<<2048, 256, 0, stream>>>(off, colval, out, k);
        transform_fused<<<1024, 256, 0, stream>>>(
            W_gc + (size_t)k * EMB * EMB, b_gc + (size_t)k * EMB,
            W_bi + (size_t)k * EMB * EMB, b_bi + (size_t)k * EMB,
            out, k);
    }
}

// Round 5
// 860.568 us; speedup vs baseline: 3.3997x; 1.1192x over previous
//
#include <hip/hip_runtime.h>

#define N_USERS 100000
#define N_ITEMS 100000
#define N_NODES 200000
#define NNZ     3200000
#define EMB     64
#define HOPS    3
#define SLOTS   (HOPS + 1)
#define ROWSTRIDE (SLOTS * EMB)   // 256 floats per node row in out

#define BROWS 1024                               // rows per bucket
#define NBUCK ((N_NODES + BROWS - 1) / BROWS)    // 196
#define CAPB  20                                 // reg entries per thread (csr_bucket)
#define EPB   2048                               // edges per round (bucketize)

// pack: x = (rlocal<<18) | col   (rlocal<1024 -> 10b, col<200000<2^18 -> 18b)

// ---------------------------------------------------------------------------
// out[:, 0, :] = concat(user_emb, item_emb)   (float4 copy)
// ---------------------------------------------------------------------------
__global__ __launch_bounds__(256) void init_ego(
    const float4* __restrict__ user_emb,
    const float4* __restrict__ item_emb,
    float4* __restrict__ out)
{
    int idx = blockIdx.x * blockDim.x + threadIdx.x;
    if (idx >= N_NODES * 16) return;
    int n = idx >> 4;
    int q = idx & 15;
    float4 v = (n < N_USERS) ? user_emb[(size_t)n * 16 + q]
                             : item_emb[(size_t)(n - N_USERS) * 16 + q];
    out[(size_t)n * (SLOTS * 16) + q] = v;
}

// ---------------------------------------------------------------------------
// bucket histogram: bcnt[b] = #edges with rows[e]>>10 == b  (LDS-staged)
// ---------------------------------------------------------------------------
__global__ __launch_bounds__(256) void hist_buckets(
    const int* __restrict__ rows, int* __restrict__ bcnt)
{
    __shared__ int h[NBUCK];
    int t = threadIdx.x;
    if (t < NBUCK) h[t] = 0;
    __syncthreads();
    for (int e = blockIdx.x * blockDim.x + t; e < NNZ; e += gridDim.x * blockDim.x)
        atomicAdd(&h[rows[e] >> 10], 1);
    __syncthreads();
    if (t < NBUCK && h[t]) atomicAdd(&bcnt[t], h[t]);
}

// ---------------------------------------------------------------------------
// exclusive scan of 196 bucket counts -> boff[0..NBUCK], gcur init, off[N]
// ---------------------------------------------------------------------------
__global__ __launch_bounds__(256) void scan196(
    const int* __restrict__ bcnt, int* __restrict__ boff,
    int* __restrict__ gcur, int* __restrict__ off)
{
    __shared__ int sdata[256];
    int t = threadIdx.x;
    int v = (t < NBUCK) ? bcnt[t] : 0;
    sdata[t] = v;
    __syncthreads();
    #pragma unroll
    for (int ofs = 1; ofs < 256; ofs <<= 1) {
        int add = (t >= ofs) ? sdata[t - ofs] : 0;
        __syncthreads();
        sdata[t] += add;
        __syncthreads();
    }
    if (t < NBUCK) {
        int excl = sdata[t] - v;
        boff[t] = excl;
        gcur[t] = excl;
    }
    if (t == NBUCK - 1) boff[NBUCK] = sdata[t];   // = NNZ
    if (t == 0) off[N_NODES] = NNZ;
}

// ---------------------------------------------------------------------------
// bucketize: block-local counting sort of EPB-edge rounds into bucket-grouped
// tmp[]. Per round: LDS histogram -> scan -> global reservation -> stage in
// bucket-sorted LDS order with precomputed dest -> parallel coalesced flush.
// ---------------------------------------------------------------------------
__global__ __launch_bounds__(256) void bucketize(
    const int* __restrict__ rows, const int* __restrict__ cols,
    const float* __restrict__ vals,
    int* __restrict__ gcur, int2* __restrict__ tmp)
{
    __shared__ int hist[NBUCK];
    __shared__ int lofs[NBUCK];
    __shared__ int cnt2[NBUCK];
    __shared__ int gbase[NBUCK];
    __shared__ int sscan[256];
    __shared__ int2 stage[EPB];      // 16 KB
    __shared__ int  sdst[EPB];       // 8 KB

    int t = threadIdx.x;

    for (int base = blockIdx.x * EPB; base < NNZ; base += gridDim.x * EPB) {
        int e1 = min(base + EPB, NNZ);
        int cnt = e1 - base;

        if (t < NBUCK) { hist[t] = 0; cnt2[t] = 0; }
        __syncthreads();

        int  myb[8];
        int2 mypk[8];
        #pragma unroll
        for (int u = 0; u < 8; ++u) {
            int idx = base + u * 256 + t;
            myb[u] = -1;
            if (idx < e1) {
                int r = rows[idx];
                int c = cols[idx];
                float v = vals[idx];
                myb[u] = r >> 10;
                mypk[u].x = ((r & 1023) << 18) | c;
                mypk[u].y = __float_as_int(v);
                atomicAdd(&hist[myb[u]], 1);
            }
        }
        __syncthreads();

        // exclusive scan of hist[0..NBUCK) (Hillis-Steele over 256)
        int hv = (t < NBUCK) ? hist[t] : 0;
        sscan[t] = hv;
        __syncthreads();
        #pragma unroll
        for (int o = 1; o < 256; o <<= 1) {
            int add = (t >= o) ? sscan[t - o] : 0;
            __syncthreads();
            sscan[t] += add;
            __syncthreads();
        }
        if (t < NBUCK) {
            lofs[t] = sscan[t] - hv;
            gbase[t] = atomicAdd(&gcur[t], hv);   // reserve global range
        }
        __syncthreads();

        // stage entries in bucket-sorted order, record global dest
        #pragma unroll
        for (int u = 0; u < 8; ++u) {
            if (myb[u] >= 0) {
                int rank = atomicAdd(&cnt2[myb[u]], 1);
                int p = lofs[myb[u]] + rank;
                stage[p] = mypk[u];
                sdst[p]  = gbase[myb[u]] + rank;
            }
        }
        __syncthreads();

        // parallel coalesced flush (runs of ~EPB/NBUCK consecutive dests)
        for (int j = t; j < cnt; j += 256)
            tmp[sdst[j]] = stage[j];
        __syncthreads();
    }
}

// ---------------------------------------------------------------------------
// csr_bucket: one block per bucket. Loads the bucket's edges into registers
// (in-place safe), builds per-row counts + scan in LDS, writes off[], then
// scatters final CSR (col,val) into the bucket's own range (L2-resident).
// ---------------------------------------------------------------------------
__global__ __launch_bounds__(1024) void csr_bucket(
    const int* __restrict__ boff, int2* __restrict__ colval,
    int* __restrict__ off)
{
    __shared__ int curL[BROWS];
    __shared__ int sWaveSum[16];
    __shared__ int sWaveOff[16];

    int b = blockIdx.x;
    int t = threadIdx.x;
    int s = boff[b];
    int e = boff[b + 1];

    int2 ent[CAPB];
    #pragma unroll
    for (int i = 0; i < CAPB; ++i) {
        int idx = s + i * 1024 + t;
        if (idx < e) ent[i] = colval[idx];
    }

    curL[t] = 0;
    __syncthreads();

    #pragma unroll
    for (int i = 0; i < CAPB; ++i) {
        int idx = s + i * 1024 + t;
        if (idx < e) atomicAdd(&curL[ent[i].x >> 18], 1);
    }
    __syncthreads();

    int lane = t & 63;
    int wid  = t >> 6;
    int v = curL[t];
    int inc = v;
    #pragma unroll
    for (int o = 1; o < 64; o <<= 1) {
        int up = __shfl_up(inc, o);
        if (lane >= o) inc += up;
    }
    if (lane == 63) sWaveSum[wid] = inc;
    __syncthreads();
    if (t < 16) {
        int w = sWaveSum[t];
        int wi = w;
        #pragma unroll
        for (int o = 1; o < 16; o <<= 1) {
            int up = __shfl_up(wi, o);
            if (t >= o) wi += up;
        }
        sWaveOff[t] = wi - w;
    }
    __syncthreads();
    int excl = inc - v + sWaveOff[wid];

    int row = b * BROWS + t;
    if (row < N_NODES) off[row] = s + excl;
    __syncthreads();
    curL[t] = s + excl;
    __syncthreads();

    #pragma unroll
    for (int i = 0; i < CAPB; ++i) {
        int idx = s + i * 1024 + t;
        if (idx < e) {
            int rl = ent[i].x >> 18;
            int p = atomicAdd(&curL[rl], 1);
            int2 cv;
            cv.x = ent[i].x & 0x3FFFF;
            cv.y = ent[i].y;
            colval[p] = cv;
        }
    }
}

// ---------------------------------------------------------------------------
// gather: side[n][d] = sum_e vals[e]*ego[cols[e]][d], written to out slot k+1
// ---------------------------------------------------------------------------
__global__ __launch_bounds__(256, 4) void gather_side(
    const int* __restrict__ off, const int2* __restrict__ colval,
    float* __restrict__ out, int k)
{
    int d = threadIdx.x & 63;
    int gw = (int)((blockIdx.x * (size_t)blockDim.x + threadIdx.x) >> 6);
    int nw = (gridDim.x * blockDim.x) >> 6;

    const float* egoK = out + (size_t)k * EMB;
    float* dst = out + (size_t)(k + 1) * EMB;

    for (int n = gw; n < N_NODES; n += nw) {
        int beg = __builtin_amdgcn_readfirstlane(off[n]);
        int end = __builtin_amdgcn_readfirstlane(off[n + 1]);
        float a0 = 0.f, a1 = 0.f, a2 = 0.f, a3 = 0.f;
        int e = beg;
        for (; e + 8 <= end; e += 8) {
            int2 cv[8];
            #pragma unroll
            for (int u = 0; u < 8; ++u) cv[u] = colval[e + u];
            float x[8];
            #pragma unroll
            for (int u = 0; u < 8; ++u)
                x[u] = egoK[(unsigned)cv[u].x * (unsigned)ROWSTRIDE + (unsigned)d];
            a0 = fmaf(__int_as_float(cv[0].y), x[0], a0);
            a1 = fmaf(__int_as_float(cv[1].y), x[1], a1);
            a2 = fmaf(__int_as_float(cv[2].y), x[2], a2);
            a3 = fmaf(__int_as_float(cv[3].y), x[3], a3);
            a0 = fmaf(__int_as_float(cv[4].y), x[4], a0);
            a1 = fmaf(__int_as_float(cv[5].y), x[5], a1);
            a2 = fmaf(__int_as_float(cv[6].y), x[6], a2);
            a3 = fmaf(__int_as_float(cv[7].y), x[7], a3);
        }
        for (; e + 2 <= end; e += 2) {
            int2 c0 = colval[e];
            int2 c1 = colval[e + 1];
            float x0 = egoK[(unsigned)c0.x * (unsigned)ROWSTRIDE + (unsigned)d];
            float x1 = egoK[(unsigned)c1.x * (unsigned)ROWSTRIDE + (unsigned)d];
            a0 = fmaf(__int_as_float(c0.y), x0, a0);
            a1 = fmaf(__int_as_float(c1.y), x1, a1);
        }
        if (e < end) {
            int2 c = colval[e];
            a2 = fmaf(__int_as_float(c.y),
                      egoK[(unsigned)c.x * (unsigned)ROWSTRIDE + (unsigned)d], a2);
        }
        dst[(size_t)n * ROWSTRIDE + d] = (a0 + a1) + (a2 + a3);
    }
}

// ---------------------------------------------------------------------------
// transform (+fused normalization)
// ---------------------------------------------------------------------------
__global__ __launch_bounds__(256, 2) void transform_fused(
    const float* __restrict__ Wg, const float* __restrict__ bg,
    const float* __restrict__ Wb, const float* __restrict__ bb,
    float* __restrict__ out, int k)
{
    int d = threadIdx.x & 63;
    int gw = (int)((blockIdx.x * (size_t)blockDim.x + threadIdx.x) >> 6);
    int nw = (gridDim.x * blockDim.x) >> 6;

    float wg[EMB], wb[EMB];
    #pragma unroll
    for (int j = 0; j < EMB; ++j) {
        wg[j] = Wg[j * EMB + d];
        wb[j] = Wb[j * EMB + d];
    }
    float bias = bg[d] + bb[d];

    float* slotK  = out + (size_t)k * EMB;
    float* slotK1 = out + (size_t)(k + 1) * EMB;
    const bool lastHop = (k == HOPS - 1);

    for (int n = gw; n < N_NODES; n += nw) {
        size_t base = (size_t)n * ROWSTRIDE;
        float s  = slotK1[base + d];
        float eg = slotK [base + d];
        float es = eg * s;

        float o0 = bias, o1 = 0.f, o2 = 0.f, o3 = 0.f;
        #pragma unroll
        for (int j = 0; j < EMB; j += 2) {
            float sj0 = __uint_as_float(__builtin_amdgcn_readlane(__float_as_uint(s),  j));
            float ej0 = __uint_as_float(__builtin_amdgcn_readlane(__float_as_uint(es), j));
            float sj1 = __uint_as_float(__builtin_amdgcn_readlane(__float_as_uint(s),  j + 1));
            float ej1 = __uint_as_float(__builtin_amdgcn_readlane(__float_as_uint(es), j + 1));
            o0 = fmaf(sj0, wg[j],     o0);
            o1 = fmaf(ej0, wb[j],     o1);
            o2 = fmaf(sj1, wg[j + 1], o2);
            o3 = fmaf(ej1, wb[j + 1], o3);
        }
        float o = (o0 + o1) + (o2 + o3);
        o = (o > 0.f) ? o : 0.2f * o;

        if (lastHop) {
            float ss = o * o;
            #pragma unroll
            for (int m = 32; m > 0; m >>= 1) ss += __shfl_xor(ss, m);
            o = o / fmaxf(sqrtf(ss), 1e-12f);
        }
        slotK1[base + d] = o;

        if (k >= 1) {
            float ss = eg * eg;
            #pragma unroll
            for (int m = 32; m > 0; m >>= 1) ss += __shfl_xor(ss, m);
            slotK[base + d] = eg / fmaxf(sqrtf(ss), 1e-12f);
        }
    }
}

extern "C" void kernel_launch(void* const* d_in, const int* in_sizes, int n_in,
                              void* d_out, int out_size, void* d_ws, size_t ws_size,
                              hipStream_t stream)
{
    const int*   rows     = (const int*)d_in[0];
    const int*   cols     = (const int*)d_in[1];
    const float* vals     = (const float*)d_in[2];
    const float* user_emb = (const float*)d_in[3];
    const float* item_emb = (const float*)d_in[4];
    const float* W_gc     = (const float*)d_in[5];
    const float* b_gc     = (const float*)d_in[6];
    const float* W_bi     = (const float*)d_in[7];
    const float* b_bi     = (const float*)d_in[8];
    float* out = (float*)d_out;

    // ws layout (ints): bcnt[196] | boff[197] | gcur[196] | off[N+1] | colval[NNZ int2]
    int* ws_i = (int*)d_ws;
    int* bcnt = ws_i;                        // NBUCK
    int* boff = bcnt + NBUCK;                // NBUCK + 1
    int* gcur = boff + NBUCK + 1;            // NBUCK
    int* off  = gcur + NBUCK;                // N_NODES + 1
    int2* colval = (int2*)(off + N_NODES + 1);   // NNZ

    // --- CSR build ---
    hipMemsetAsync(bcnt, 0, NBUCK * sizeof(int), stream);
    hist_buckets<<<1024, 256, 0, stream>>>(rows, bcnt);
    scan196<<<1, 256, 0, stream>>>(bcnt, boff, gcur, off);
    bucketize<<<512, 256, 0, stream>>>(rows, cols, vals, gcur, colval);
    csr_bucket<<<NBUCK, 1024, 0, stream>>>(boff, colval, off);

    // --- slot 0 = initial ego ---
    init_ego<<<(N_NODES * 16 + 255) / 256, 256, 0, stream>>>(
        (const float4*)user_emb, (const float4*)item_emb, (float4*)out);

    // --- hops ---
    for (int k = 0; k < HOPS; ++k) {
        gather_side<<<2048, 256, 0, stream>>>(off, colval, out, k);
        transform_fused<<<1024, 256, 0, stream>>>(
            W_gc + (size_t)k * EMB * EMB, b_gc + (size_t)k * EMB,
            W_bi + (size_t)k * EMB * EMB, b_bi + (size_t)k * EMB,
            out, k);
    }
}

// Round 6
// 741.327 us; speedup vs baseline: 3.9465x; 1.1608x over previous
//
#include <hip/hip_runtime.h>

#define N_USERS 100000
#define N_ITEMS 100000
#define N_NODES 200000
#define NNZ     3200000
#define EMB     64
#define HOPS    3
#define SLOTS   (HOPS + 1)
#define ROWSTRIDE (SLOTS * EMB)   // 256 floats per node row in out

#define BROWS 1024                               // rows per bucket
#define NBUCK ((N_NODES + BROWS - 1) / BROWS)    // 196
#define CAPB  20                                 // reg entries per thread (csr_bucket)
#define EPB   2048                               // edges per round (bucketize)
#define TILE  64                                 // nodes per transform block
#define LPAD  33                                 // LDS row pitch (bank-conflict-free)

// pack: x = (rlocal<<18) | col

// ---------------------------------------------------------------------------
__global__ __launch_bounds__(256) void init_ego(
    const float4* __restrict__ user_emb,
    const float4* __restrict__ item_emb,
    float4* __restrict__ out)
{
    int idx = blockIdx.x * blockDim.x + threadIdx.x;
    if (idx >= N_NODES * 16) return;
    int n = idx >> 4;
    int q = idx & 15;
    float4 v = (n < N_USERS) ? user_emb[(size_t)n * 16 + q]
                             : item_emb[(size_t)(n - N_USERS) * 16 + q];
    out[(size_t)n * (SLOTS * 16) + q] = v;
}

// ---------------------------------------------------------------------------
__global__ __launch_bounds__(256) void hist_buckets(
    const int* __restrict__ rows, int* __restrict__ bcnt)
{
    __shared__ int h[NBUCK];
    int t = threadIdx.x;
    if (t < NBUCK) h[t] = 0;
    __syncthreads();
    for (int e = blockIdx.x * blockDim.x + t; e < NNZ; e += gridDim.x * blockDim.x)
        atomicAdd(&h[rows[e] >> 10], 1);
    __syncthreads();
    if (t < NBUCK && h[t]) atomicAdd(&bcnt[t], h[t]);
}

// ---------------------------------------------------------------------------
__global__ __launch_bounds__(256) void scan196(
    const int* __restrict__ bcnt, int* __restrict__ boff,
    int* __restrict__ gcur, int* __restrict__ off)
{
    __shared__ int sdata[256];
    int t = threadIdx.x;
    int v = (t < NBUCK) ? bcnt[t] : 0;
    sdata[t] = v;
    __syncthreads();
    #pragma unroll
    for (int ofs = 1; ofs < 256; ofs <<= 1) {
        int add = (t >= ofs) ? sdata[t - ofs] : 0;
        __syncthreads();
        sdata[t] += add;
        __syncthreads();
    }
    if (t < NBUCK) {
        int excl = sdata[t] - v;
        boff[t] = excl;
        gcur[t] = excl;
    }
    if (t == NBUCK - 1) boff[NBUCK] = sdata[t];
    if (t == 0) off[N_NODES] = NNZ;
}

// ---------------------------------------------------------------------------
__global__ __launch_bounds__(256) void bucketize(
    const int* __restrict__ rows, const int* __restrict__ cols,
    const float* __restrict__ vals,
    int* __restrict__ gcur, int2* __restrict__ tmp)
{
    __shared__ int hist[NBUCK];
    __shared__ int lofs[NBUCK];
    __shared__ int cnt2[NBUCK];
    __shared__ int gbase[NBUCK];
    __shared__ int sscan[256];
    __shared__ int2 stage[EPB];
    __shared__ int  sdst[EPB];

    int t = threadIdx.x;

    for (int base = blockIdx.x * EPB; base < NNZ; base += gridDim.x * EPB) {
        int e1 = min(base + EPB, NNZ);
        int cnt = e1 - base;

        if (t < NBUCK) { hist[t] = 0; cnt2[t] = 0; }
        __syncthreads();

        int  myb[8];
        int2 mypk[8];
        #pragma unroll
        for (int u = 0; u < 8; ++u) {
            int idx = base + u * 256 + t;
            myb[u] = -1;
            if (idx < e1) {
                int r = rows[idx];
                int c = cols[idx];
                float v = vals[idx];
                myb[u] = r >> 10;
                mypk[u].x = ((r & 1023) << 18) | c;
                mypk[u].y = __float_as_int(v);
                atomicAdd(&hist[myb[u]], 1);
            }
        }
        __syncthreads();

        int hv = (t < NBUCK) ? hist[t] : 0;
        sscan[t] = hv;
        __syncthreads();
        #pragma unroll
        for (int o = 1; o < 256; o <<= 1) {
            int add = (t >= o) ? sscan[t - o] : 0;
            __syncthreads();
            sscan[t] += add;
            __syncthreads();
        }
        if (t < NBUCK) {
            lofs[t] = sscan[t] - hv;
            gbase[t] = atomicAdd(&gcur[t], hv);
        }
        __syncthreads();

        #pragma unroll
        for (int u = 0; u < 8; ++u) {
            if (myb[u] >= 0) {
                int rank = atomicAdd(&cnt2[myb[u]], 1);
                int p = lofs[myb[u]] + rank;
                stage[p] = mypk[u];
                sdst[p]  = gbase[myb[u]] + rank;
            }
        }
        __syncthreads();

        for (int j = t; j < cnt; j += 256)
            tmp[sdst[j]] = stage[j];
        __syncthreads();
    }
}

// ---------------------------------------------------------------------------
__global__ __launch_bounds__(1024) void csr_bucket(
    const int* __restrict__ boff, int2* __restrict__ colval,
    int* __restrict__ off)
{
    __shared__ int curL[BROWS];
    __shared__ int sWaveSum[16];
    __shared__ int sWaveOff[16];

    int b = blockIdx.x;
    int t = threadIdx.x;
    int s = boff[b];
    int e = boff[b + 1];

    int2 ent[CAPB];
    #pragma unroll
    for (int i = 0; i < CAPB; ++i) {
        int idx = s + i * 1024 + t;
        if (idx < e) ent[i] = colval[idx];
    }

    curL[t] = 0;
    __syncthreads();

    #pragma unroll
    for (int i = 0; i < CAPB; ++i) {
        int idx = s + i * 1024 + t;
        if (idx < e) atomicAdd(&curL[ent[i].x >> 18], 1);
    }
    __syncthreads();

    int lane = t & 63;
    int wid  = t >> 6;
    int v = curL[t];
    int inc = v;
    #pragma unroll
    for (int o = 1; o < 64; o <<= 1) {
        int up = __shfl_up(inc, o);
        if (lane >= o) inc += up;
    }
    if (lane == 63) sWaveSum[wid] = inc;
    __syncthreads();
    if (t < 16) {
        int w = sWaveSum[t];
        int wi = w;
        #pragma unroll
        for (int o = 1; o < 16; o <<= 1) {
            int up = __shfl_up(wi, o);
            if (t >= o) wi += up;
        }
        sWaveOff[t] = wi - w;
    }
    __syncthreads();
    int excl = inc - v + sWaveOff[wid];

    int row = b * BROWS + t;
    if (row < N_NODES) off[row] = s + excl;
    __syncthreads();
    curL[t] = s + excl;
    __syncthreads();

    #pragma unroll
    for (int i = 0; i < CAPB; ++i) {
        int idx = s + i * 1024 + t;
        if (idx < e) {
            int rl = ent[i].x >> 18;
            int p = atomicAdd(&curL[rl], 1);
            int2 cv;
            cv.x = ent[i].x & 0x3FFFF;
            cv.y = ent[i].y;
            colval[p] = cv;
        }
    }
}

// ---------------------------------------------------------------------------
__global__ __launch_bounds__(256, 4) void gather_side(
    const int* __restrict__ off, const int2* __restrict__ colval,
    float* __restrict__ out, int k)
{
    int d = threadIdx.x & 63;
    int gw = (int)((blockIdx.x * (size_t)blockDim.x + threadIdx.x) >> 6);
    int nw = (gridDim.x * blockDim.x) >> 6;

    const float* egoK = out + (size_t)k * EMB;
    float* dst = out + (size_t)(k + 1) * EMB;

    for (int n = gw; n < N_NODES; n += nw) {
        int beg = __builtin_amdgcn_readfirstlane(off[n]);
        int end = __builtin_amdgcn_readfirstlane(off[n + 1]);
        float a0 = 0.f, a1 = 0.f, a2 = 0.f, a3 = 0.f;
        int e = beg;
        for (; e + 8 <= end; e += 8) {
            int2 cv[8];
            #pragma unroll
            for (int u = 0; u < 8; ++u) cv[u] = colval[e + u];
            float x[8];
            #pragma unroll
            for (int u = 0; u < 8; ++u)
                x[u] = egoK[(unsigned)cv[u].x * (unsigned)ROWSTRIDE + (unsigned)d];
            a0 = fmaf(__int_as_float(cv[0].y), x[0], a0);
            a1 = fmaf(__int_as_float(cv[1].y), x[1], a1);
            a2 = fmaf(__int_as_float(cv[2].y), x[2], a2);
            a3 = fmaf(__int_as_float(cv[3].y), x[3], a3);
            a0 = fmaf(__int_as_float(cv[4].y), x[4], a0);
            a1 = fmaf(__int_as_float(cv[5].y), x[5], a1);
            a2 = fmaf(__int_as_float(cv[6].y), x[6], a2);
            a3 = fmaf(__int_as_float(cv[7].y), x[7], a3);
        }
        for (; e + 2 <= end; e += 2) {
            int2 c0 = colval[e];
            int2 c1 = colval[e + 1];
            float x0 = egoK[(unsigned)c0.x * (unsigned)ROWSTRIDE + (unsigned)d];
            float x1 = egoK[(unsigned)c1.x * (unsigned)ROWSTRIDE + (unsigned)d];
            a0 = fmaf(__int_as_float(c0.y), x0, a0);
            a1 = fmaf(__int_as_float(c1.y), x1, a1);
        }
        if (e < end) {
            int2 c = colval[e];
            a2 = fmaf(__int_as_float(c.y),
                      egoK[(unsigned)c.x * (unsigned)ROWSTRIDE + (unsigned)d], a2);
        }
        dst[(size_t)n * ROWSTRIDE + d] = (a0 + a1) + (a2 + a3);
    }
}

// ---------------------------------------------------------------------------
// transform v2: block = 64-node tile, 4 waves; lane = node, wave owns a
// 16-wide d-chunk. s/es staged transposed in LDS; W indices wave-uniform ->
// SGPR operands in FMA. Last hop's output row-norm fused (LDS 4-partial sum).
// ---------------------------------------------------------------------------
__global__ __launch_bounds__(256) void transform_v2(
    const float* __restrict__ Wg, const float* __restrict__ bg,
    const float* __restrict__ Wb, const float* __restrict__ bb,
    float* __restrict__ out, int k)
{
    __shared__ float sS [TILE * LPAD];
    __shared__ float sES[TILE * LPAD];
    __shared__ float rsum[4][TILE];

    int t = threadIdx.x;
    int lane = t & 63;                                        // node within tile
    int dbase = __builtin_amdgcn_readfirstlane((t >> 6) * 16); // wave's d-chunk

    const float* slotK  = out + (size_t)k * EMB;
    float* slotK1 = out + (size_t)(k + 1) * EMB;
    const bool lastHop = (k == HOPS - 1);

    int tile = blockIdx.x;
    int node0 = tile * TILE;

    float acc[16];
    #pragma unroll
    for (int di = 0; di < 16; ++di) acc[di] = 0.f;

    // staging thread mapping: 8 lanes x float4 cover one node's 32 j's
    int f4 = (t & 7) * 4;     // j offset within phase
    int nn = t >> 3;          // 0..31

    for (int p = 0; p < 2; ++p) {
        // ---- stage s, es for j in [32p, 32p+32) ----
        #pragma unroll
        for (int rep = 0; rep < 2; ++rep) {
            int n = nn + 32 * rep;
            size_t base = (size_t)(node0 + n) * ROWSTRIDE + 32 * p + f4;
            float4 s4 = *(const float4*)(slotK1 + base);
            float4 e4 = *(const float4*)(slotK  + base);
            int lb = n * LPAD + f4;
            sS [lb + 0] = s4.x; sS [lb + 1] = s4.y; sS [lb + 2] = s4.z; sS [lb + 3] = s4.w;
            sES[lb + 0] = e4.x * s4.x; sES[lb + 1] = e4.y * s4.y;
            sES[lb + 2] = e4.z * s4.z; sES[lb + 3] = e4.w * s4.w;
        }
        __syncthreads();

        // ---- compute: 32 j-steps, W via scalar loads ----
        for (int jj = 0; jj < 32; ++jj) {
            float sv = sS [lane * LPAD + jj];
            float ev = sES[lane * LPAD + jj];
            int j = 32 * p + jj;
            const float* wgrow = Wg + j * EMB + dbase;
            const float* wbrow = Wb + j * EMB + dbase;
            #pragma unroll
            for (int di = 0; di < 16; ++di)
                acc[di] = fmaf(sv, wgrow[di], fmaf(ev, wbrow[di], acc[di]));
        }
        __syncthreads();
    }

    // ---- epilogue: bias, leaky, (last-hop norm), store ----
    float o[16];
    #pragma unroll
    for (int di = 0; di < 16; ++di) {
        float v = acc[di] + (bg[dbase + di] + bb[dbase + di]);
        o[di] = (v > 0.f) ? v : 0.2f * v;
    }

    float scale = 1.f;
    if (lastHop) {
        float ps = 0.f;
        #pragma unroll
        for (int di = 0; di < 16; ++di) ps = fmaf(o[di], o[di], ps);
        rsum[t >> 6][lane] = ps;
        __syncthreads();
        float tot = rsum[0][lane] + rsum[1][lane] + rsum[2][lane] + rsum[3][lane];
        scale = 1.f / fmaxf(sqrtf(tot), 1e-12f);
    }

    float* dstp = slotK1 + (size_t)(node0 + lane) * ROWSTRIDE + dbase;
    #pragma unroll
    for (int q = 0; q < 4; ++q) {
        float4 o4;
        o4.x = o[4 * q + 0] * scale;
        o4.y = o[4 * q + 1] * scale;
        o4.z = o[4 * q + 2] * scale;
        o4.w = o[4 * q + 3] * scale;
        *(float4*)(dstp + 4 * q) = o4;
    }
}

// ---------------------------------------------------------------------------
// L2-normalize out slots 1..2 in place (slot 3 normalized in transform_v2).
// ---------------------------------------------------------------------------
__global__ __launch_bounds__(256) void normalize_slots12(float* __restrict__ out)
{
    int w = (int)((blockIdx.x * (size_t)blockDim.x + threadIdx.x) >> 6);
    int d = threadIdx.x & 63;
    int n = w >> 1;
    int slot = 1 + (w & 1);
    if (n >= N_NODES) return;
    size_t idx = (size_t)n * ROWSTRIDE + (size_t)slot * EMB + d;
    float v = out[idx];
    float ss = v * v;
    #pragma unroll
    for (int off = 32; off > 0; off >>= 1) ss += __shfl_xor(ss, off);
    float nrm = fmaxf(sqrtf(ss), 1e-12f);
    out[idx] = v / nrm;
}

extern "C" void kernel_launch(void* const* d_in, const int* in_sizes, int n_in,
                              void* d_out, int out_size, void* d_ws, size_t ws_size,
                              hipStream_t stream)
{
    const int*   rows     = (const int*)d_in[0];
    const int*   cols     = (const int*)d_in[1];
    const float* vals     = (const float*)d_in[2];
    const float* user_emb = (const float*)d_in[3];
    const float* item_emb = (const float*)d_in[4];
    const float* W_gc     = (const float*)d_in[5];
    const float* b_gc     = (const float*)d_in[6];
    const float* W_bi     = (const float*)d_in[7];
    const float* b_bi     = (const float*)d_in[8];
    float* out = (float*)d_out;

    // ws layout (ints): bcnt[196] | boff[197] | gcur[196] | off[N+1] | colval[NNZ int2]
    int* ws_i = (int*)d_ws;
    int* bcnt = ws_i;
    int* boff = bcnt + NBUCK;
    int* gcur = boff + NBUCK + 1;
    int* off  = gcur + NBUCK;
    int2* colval = (int2*)(off + N_NODES + 1);

    // --- CSR build ---
    hipMemsetAsync(bcnt, 0, NBUCK * sizeof(int), stream);
    hist_buckets<<<1024, 256, 0, stream>>>(rows, bcnt);
    scan196<<<1, 256, 0, stream>>>(bcnt, boff, gcur, off);
    bucketize<<<512, 256, 0, stream>>>(rows, cols, vals, gcur, colval);
    csr_bucket<<<NBUCK, 1024, 0, stream>>>(boff, colval, off);

    // --- slot 0 = initial ego ---
    init_ego<<<(N_NODES * 16 + 255) / 256, 256, 0, stream>>>(
        (const float4*)user_emb, (const float4*)item_emb, (float4*)out);

    // --- hops ---
    for (int k = 0; k < HOPS; ++k) {
        gather_side<<<2048, 256, 0, stream>>>(off, colval, out, k);
        transform_v2<<<N_NODES / TILE, 256, 0, stream>>>(
            W_gc + (size_t)k * EMB * EMB, b_gc + (size_t)k * EMB,
            W_bi + (size_t)k * EMB * EMB, b_bi + (size_t)k * EMB,
            out, k);
    }

    normalize_slots12<<<(N_NODES * 2 * 64 + 255) / 256, 256, 0, stream>>>(out);
}

// Round 7
// 740.526 us; speedup vs baseline: 3.9508x; 1.0011x over previous
//
#include <hip/hip_runtime.h>

#define N_USERS 100000
#define N_ITEMS 100000
#define N_NODES 200000
#define NNZ     3200000
#define EMB     64
#define HOPS    3
#define SLOTS   (HOPS + 1)
#define ROWSTRIDE (SLOTS * EMB)   // 256 floats per node row in out

#define BROWS 1024                               // rows per bucket
#define NBUCK ((N_NODES + BROWS - 1) / BROWS)    // 196
#define CAPB  20                                 // reg entries per thread (csr_bucket)
#define EPB   2048                               // edges per round (bucketize)
#define TILE  64                                 // nodes per transform block
#define LPAD  33                                 // LDS row pitch

// final CSR entry: cv = (col<<14) | val14   (col<2^18, val in [0,1) as 14-bit fixed)
// build-time row id: separate ushort rl = row & 1023

__device__ __forceinline__ float bf2f(unsigned short h) {
    return __uint_as_float(((unsigned int)h) << 16);
}
__device__ __forceinline__ unsigned int f2bfbits(float f) {
    unsigned int u = __float_as_uint(f);
    return (u + 0x7FFFu + ((u >> 16) & 1u)) >> 16;   // RNE
}

// ---------------------------------------------------------------------------
// out[:, 0, :] = concat(user_emb, item_emb); also egoBf = bf16(ego0)
// ---------------------------------------------------------------------------
__global__ __launch_bounds__(256) void init_ego(
    const float4* __restrict__ user_emb,
    const float4* __restrict__ item_emb,
    float4* __restrict__ out,
    unsigned short* __restrict__ egoBf)
{
    int idx = blockIdx.x * blockDim.x + threadIdx.x;
    if (idx >= N_NODES * 16) return;
    int n = idx >> 4;
    int q = idx & 15;
    float4 v = (n < N_USERS) ? user_emb[(size_t)n * 16 + q]
                             : item_emb[(size_t)(n - N_USERS) * 16 + q];
    out[(size_t)n * (SLOTS * 16) + q] = v;
    uint2 p;
    p.x = f2bfbits(v.x) | (f2bfbits(v.y) << 16);
    p.y = f2bfbits(v.z) | (f2bfbits(v.w) << 16);
    *(uint2*)(egoBf + (size_t)n * EMB + q * 4) = p;
}

// ---------------------------------------------------------------------------
__global__ __launch_bounds__(256) void hist_buckets(
    const int* __restrict__ rows, int* __restrict__ bcnt)
{
    __shared__ int h[NBUCK];
    int t = threadIdx.x;
    if (t < NBUCK) h[t] = 0;
    __syncthreads();
    for (int e = blockIdx.x * blockDim.x + t; e < NNZ; e += gridDim.x * blockDim.x)
        atomicAdd(&h[rows[e] >> 10], 1);
    __syncthreads();
    if (t < NBUCK && h[t]) atomicAdd(&bcnt[t], h[t]);
}

// ---------------------------------------------------------------------------
__global__ __launch_bounds__(256) void scan196(
    const int* __restrict__ bcnt, int* __restrict__ boff,
    int* __restrict__ gcur, int* __restrict__ off)
{
    __shared__ int sdata[256];
    int t = threadIdx.x;
    int v = (t < NBUCK) ? bcnt[t] : 0;
    sdata[t] = v;
    __syncthreads();
    #pragma unroll
    for (int ofs = 1; ofs < 256; ofs <<= 1) {
        int add = (t >= ofs) ? sdata[t - ofs] : 0;
        __syncthreads();
        sdata[t] += add;
        __syncthreads();
    }
    if (t < NBUCK) {
        int excl = sdata[t] - v;
        boff[t] = excl;
        gcur[t] = excl;
    }
    if (t == NBUCK - 1) boff[NBUCK] = sdata[t];
    if (t == 0) off[N_NODES] = NNZ;
}

// ---------------------------------------------------------------------------
// bucketize: block-local counting sort into bucket-grouped cv[] / rl[]
// ---------------------------------------------------------------------------
__global__ __launch_bounds__(256) void bucketize(
    const int* __restrict__ rows, const int* __restrict__ cols,
    const float* __restrict__ vals,
    int* __restrict__ gcur,
    unsigned int* __restrict__ cvg, unsigned short* __restrict__ rlg)
{
    __shared__ int hist[NBUCK];
    __shared__ int lofs[NBUCK];
    __shared__ int cnt2[NBUCK];
    __shared__ int gbase[NBUCK];
    __shared__ int sscan[256];
    __shared__ unsigned int   stcv[EPB];   // 8 KB
    __shared__ unsigned short strl[EPB];   // 4 KB
    __shared__ int            sdst[EPB];   // 8 KB

    int t = threadIdx.x;

    for (int base = blockIdx.x * EPB; base < NNZ; base += gridDim.x * EPB) {
        int e1 = min(base + EPB, NNZ);
        int cnt = e1 - base;

        if (t < NBUCK) { hist[t] = 0; cnt2[t] = 0; }
        __syncthreads();

        int myb[8];
        unsigned int mycv[8];
        unsigned short myrl[8];
        #pragma unroll
        for (int u = 0; u < 8; ++u) {
            int idx = base + u * 256 + t;
            myb[u] = -1;
            if (idx < e1) {
                int r = rows[idx];
                int c = cols[idx];
                float v = vals[idx];
                myb[u] = r >> 10;
                unsigned int q14 = (unsigned int)(v * 16383.f + 0.5f);
                mycv[u] = ((unsigned int)c << 14) | q14;
                myrl[u] = (unsigned short)(r & 1023);
                atomicAdd(&hist[myb[u]], 1);
            }
        }
        __syncthreads();

        int hv = (t < NBUCK) ? hist[t] : 0;
        sscan[t] = hv;
        __syncthreads();
        #pragma unroll
        for (int o = 1; o < 256; o <<= 1) {
            int add = (t >= o) ? sscan[t - o] : 0;
            __syncthreads();
            sscan[t] += add;
            __syncthreads();
        }
        if (t < NBUCK) {
            lofs[t] = sscan[t] - hv;
            gbase[t] = atomicAdd(&gcur[t], hv);
        }
        __syncthreads();

        #pragma unroll
        for (int u = 0; u < 8; ++u) {
            if (myb[u] >= 0) {
                int rank = atomicAdd(&cnt2[myb[u]], 1);
                int p = lofs[myb[u]] + rank;
                stcv[p] = mycv[u];
                strl[p] = myrl[u];
                sdst[p] = gbase[myb[u]] + rank;
            }
        }
        __syncthreads();

        for (int j = t; j < cnt; j += 256) {
            int dp = sdst[j];
            cvg[dp] = stcv[j];
            rlg[dp] = strl[j];
        }
        __syncthreads();
    }
}

// ---------------------------------------------------------------------------
// csr_bucket: one block per bucket; in-place re-rank of cv by row
// ---------------------------------------------------------------------------
__global__ __launch_bounds__(1024) void csr_bucket(
    const int* __restrict__ boff,
    unsigned int* __restrict__ cv, const unsigned short* __restrict__ rl,
    int* __restrict__ off)
{
    __shared__ int curL[BROWS];
    __shared__ int sWaveSum[16];
    __shared__ int sWaveOff[16];

    int b = blockIdx.x;
    int t = threadIdx.x;
    int s = boff[b];
    int e = boff[b + 1];

    unsigned int  ecv[CAPB];
    unsigned short erl[CAPB];
    #pragma unroll
    for (int i = 0; i < CAPB; ++i) {
        int idx = s + i * 1024 + t;
        if (idx < e) { ecv[i] = cv[idx]; erl[i] = rl[idx]; }
    }

    curL[t] = 0;
    __syncthreads();

    #pragma unroll
    for (int i = 0; i < CAPB; ++i) {
        int idx = s + i * 1024 + t;
        if (idx < e) atomicAdd(&curL[(int)erl[i]], 1);
    }
    __syncthreads();

    int lane = t & 63;
    int wid  = t >> 6;
    int v = curL[t];
    int inc = v;
    #pragma unroll
    for (int o = 1; o < 64; o <<= 1) {
        int up = __shfl_up(inc, o);
        if (lane >= o) inc += up;
    }
    if (lane == 63) sWaveSum[wid] = inc;
    __syncthreads();
    if (t < 16) {
        int w = sWaveSum[t];
        int wi = w;
        #pragma unroll
        for (int o = 1; o < 16; o <<= 1) {
            int up = __shfl_up(wi, o);
            if (t >= o) wi += up;
        }
        sWaveOff[t] = wi - w;
    }
    __syncthreads();
    int excl = inc - v + sWaveOff[wid];

    int row = b * BROWS + t;
    if (row < N_NODES) off[row] = s + excl;
    __syncthreads();
    curL[t] = s + excl;
    __syncthreads();

    #pragma unroll
    for (int i = 0; i < CAPB; ++i) {
        int idx = s + i * 1024 + t;
        if (idx < e) {
            int p = atomicAdd(&curL[(int)erl[i]], 1);
            cv[p] = ecv[i];
        }
    }
}

// ---------------------------------------------------------------------------
// gather: side[n][d] = sum_e val(e) * egoBf[col(e)][d]  -> out slot k+1 (fp32)
// bf16 gather payload (128 B/row), 16-deep unroll
// ---------------------------------------------------------------------------
__global__ __launch_bounds__(256, 4) void gather_side(
    const int* __restrict__ off, const unsigned int* __restrict__ cv,
    const unsigned short* __restrict__ egoBf,
    float* __restrict__ out, int k)
{
    const float VS = 1.f / 16383.f;
    int d = threadIdx.x & 63;
    int gw = (int)((blockIdx.x * (size_t)blockDim.x + threadIdx.x) >> 6);
    int nw = (gridDim.x * blockDim.x) >> 6;

    float* dst = out + (size_t)(k + 1) * EMB;

    for (int n = gw; n < N_NODES; n += nw) {
        int beg = __builtin_amdgcn_readfirstlane(off[n]);
        int end = __builtin_amdgcn_readfirstlane(off[n + 1]);
        float a0 = 0.f, a1 = 0.f, a2 = 0.f, a3 = 0.f;
        int e = beg;
        for (; e + 16 <= end; e += 16) {
            unsigned int c[16];
            #pragma unroll
            for (int u = 0; u < 16; ++u) c[u] = cv[e + u];
            float x[16];
            #pragma unroll
            for (int u = 0; u < 16; ++u)
                x[u] = bf2f(egoBf[(size_t)(c[u] >> 14) * EMB + (unsigned)d]);
            #pragma unroll
            for (int u = 0; u < 16; ++u) {
                float w = (float)(c[u] & 16383u) * VS;
                if ((u & 3) == 0) a0 = fmaf(w, x[u], a0);
                else if ((u & 3) == 1) a1 = fmaf(w, x[u], a1);
                else if ((u & 3) == 2) a2 = fmaf(w, x[u], a2);
                else a3 = fmaf(w, x[u], a3);
            }
        }
        for (; e < end; ++e) {
            unsigned int cc = cv[e];
            a0 = fmaf((float)(cc & 16383u) * VS,
                      bf2f(egoBf[(size_t)(cc >> 14) * EMB + (unsigned)d]), a0);
        }
        dst[(size_t)n * ROWSTRIDE + d] = (a0 + a1) + (a2 + a3);
    }
}

// ---------------------------------------------------------------------------
// transform v3: block = 64-node tile, 4 waves; lane = node, wave owns 16 dims.
// side from slot k+1 (fp32), ego from egoBf (bf16). Writes NORMALIZED output
// to slot k+1 and (if writeNext) un-normalized bf16 ego_{k+1} into egoBf
// in place (safe: all tile reads precede epilogue writes).
// ---------------------------------------------------------------------------
__global__ __launch_bounds__(256) void transform_v3(
    const float* __restrict__ Wg, const float* __restrict__ bg,
    const float* __restrict__ Wb, const float* __restrict__ bb,
    unsigned short* __restrict__ egoBf,
    float* __restrict__ out, int k, int writeNext)
{
    __shared__ float sS [TILE * LPAD];
    __shared__ float sES[TILE * LPAD];
    __shared__ float rsum[4][TILE];

    int t = threadIdx.x;
    int lane = t & 63;
    int dbase = __builtin_amdgcn_readfirstlane((t >> 6) * 16);

    float* slotK1 = out + (size_t)(k + 1) * EMB;
    int node0 = blockIdx.x * TILE;

    float acc[16];
    #pragma unroll
    for (int di = 0; di < 16; ++di) acc[di] = 0.f;

    int f4 = (t & 7) * 4;
    int nn = t >> 3;

    for (int p = 0; p < 2; ++p) {
        #pragma unroll
        for (int rep = 0; rep < 2; ++rep) {
            int n = nn + 32 * rep;
            size_t sbase = (size_t)(node0 + n) * ROWSTRIDE + 32 * p + f4;
            float4 s4 = *(const float4*)(slotK1 + sbase);
            ushort4 e4 = *(const ushort4*)(egoBf + (size_t)(node0 + n) * EMB + 32 * p + f4);
            int lb = n * LPAD + f4;
            sS [lb + 0] = s4.x; sS [lb + 1] = s4.y; sS [lb + 2] = s4.z; sS [lb + 3] = s4.w;
            sES[lb + 0] = bf2f(e4.x) * s4.x;
            sES[lb + 1] = bf2f(e4.y) * s4.y;
            sES[lb + 2] = bf2f(e4.z) * s4.z;
            sES[lb + 3] = bf2f(e4.w) * s4.w;
        }
        __syncthreads();

        for (int jj = 0; jj < 32; ++jj) {
            float sv = sS [lane * LPAD + jj];
            float ev = sES[lane * LPAD + jj];
            int j = 32 * p + jj;
            const float* wgrow = Wg + j * EMB + dbase;
            const float* wbrow = Wb + j * EMB + dbase;
            #pragma unroll
            for (int di = 0; di < 16; ++di)
                acc[di] = fmaf(sv, wgrow[di], fmaf(ev, wbrow[di], acc[di]));
        }
        __syncthreads();
    }

    float o[16];
    #pragma unroll
    for (int di = 0; di < 16; ++di) {
        float v = acc[di] + (bg[dbase + di] + bb[dbase + di]);
        o[di] = (v > 0.f) ? v : 0.2f * v;
    }

    if (writeNext) {
        unsigned int pk[8];
        #pragma unroll
        for (int q = 0; q < 8; ++q)
            pk[q] = f2bfbits(o[2 * q]) | (f2bfbits(o[2 * q + 1]) << 16);
        uint4* dstb = (uint4*)(egoBf + (size_t)(node0 + lane) * EMB + dbase);
        uint4 pa; pa.x = pk[0]; pa.y = pk[1]; pa.z = pk[2]; pa.w = pk[3];
        uint4 pb; pb.x = pk[4]; pb.y = pk[5]; pb.z = pk[6]; pb.w = pk[7];
        dstb[0] = pa; dstb[1] = pb;
    }

    float ps = 0.f;
    #pragma unroll
    for (int di = 0; di < 16; ++di) ps = fmaf(o[di], o[di], ps);
    rsum[t >> 6][lane] = ps;
    __syncthreads();
    float tot = rsum[0][lane] + rsum[1][lane] + rsum[2][lane] + rsum[3][lane];
    float scale = 1.f / fmaxf(sqrtf(tot), 1e-12f);

    float* dstp = slotK1 + (size_t)(node0 + lane) * ROWSTRIDE + dbase;
    #pragma unroll
    for (int q = 0; q < 4; ++q) {
        float4 o4;
        o4.x = o[4 * q + 0] * scale;
        o4.y = o[4 * q + 1] * scale;
        o4.z = o[4 * q + 2] * scale;
        o4.w = o[4 * q + 3] * scale;
        *(float4*)(dstp + 4 * q) = o4;
    }
}

extern "C" void kernel_launch(void* const* d_in, const int* in_sizes, int n_in,
                              void* d_out, int out_size, void* d_ws, size_t ws_size,
                              hipStream_t stream)
{
    const int*   rows     = (const int*)d_in[0];
    const int*   cols     = (const int*)d_in[1];
    const float* vals     = (const float*)d_in[2];
    const float* user_emb = (const float*)d_in[3];
    const float* item_emb = (const float*)d_in[4];
    const float* W_gc     = (const float*)d_in[5];
    const float* b_gc     = (const float*)d_in[6];
    const float* W_bi     = (const float*)d_in[7];
    const float* b_bi     = (const float*)d_in[8];
    float* out = (float*)d_out;

    // ws: bcnt[196] boff[197] gcur[196] off[N+1] | cv[NNZ u32] | rl[NNZ u16] | egoBf[N*64 u16]
    int* ws_i = (int*)d_ws;
    int* bcnt = ws_i;
    int* boff = bcnt + NBUCK;
    int* gcur = boff + NBUCK + 1;
    int* off  = gcur + NBUCK;
    unsigned int*   cv = (unsigned int*)(off + N_NODES + 1);
    unsigned short* rl = (unsigned short*)(cv + NNZ);
    unsigned short* egoBf = rl + NNZ;   // byte offset 20,002,360 (8B aligned)

    // --- CSR build ---
    hipMemsetAsync(bcnt, 0, NBUCK * sizeof(int), stream);
    hist_buckets<<<1024, 256, 0, stream>>>(rows, bcnt);
    scan196<<<1, 256, 0, stream>>>(bcnt, boff, gcur, off);
    bucketize<<<512, 256, 0, stream>>>(rows, cols, vals, gcur, cv, rl);
    csr_bucket<<<NBUCK, 1024, 0, stream>>>(boff, cv, rl, off);

    // --- slot 0 = initial ego (+ bf16 mirror) ---
    init_ego<<<(N_NODES * 16 + 255) / 256, 256, 0, stream>>>(
        (const float4*)user_emb, (const float4*)item_emb, (float4*)out, egoBf);

    // --- hops ---
    for (int k = 0; k < HOPS; ++k) {
        gather_side<<<2048, 256, 0, stream>>>(off, cv, egoBf, out, k);
        transform_v3<<<N_NODES / TILE, 256, 0, stream>>>(
            W_gc + (size_t)k * EMB * EMB, b_gc + (size_t)k * EMB,
            W_bi + (size_t)k * EMB * EMB, b_bi + (size_t)k * EMB,
            egoBf, out, k, (k < HOPS - 1) ? 1 : 0);
    }
}